// Round 5
// 1095.375 us; speedup vs baseline: 1.1915x; 1.1915x over previous
//
#include <hip/hip_runtime.h>

typedef __attribute__((ext_vector_type(4)))  int int4v;
typedef __attribute__((ext_vector_type(16))) int i32x16;

union B16 { int4v v; signed char c[16]; };

// ---------- helpers ----------
__device__ __forceinline__ float sigm(float x){ return 1.f / (1.f + __expf(-x)); }
__device__ __forceinline__ float tanh_(float x){
  float e = __expf(-2.f * fabsf(x));        // overflow-safe
  float r = (1.f - e) / (1.f + e);
  return copysignf(r, x);
}
// h in (-1,1): h*2^15 = a1*256 + (a0 + 128), |err| <= 2^-16
__device__ __forceinline__ void h_limbs(float h, int& a1, int& a0){
  float f1 = floorf(h * 128.f);
  f1 = fminf(fmaxf(f1, -128.f), 127.f);
  float r = fmaf(h, 32768.f, f1 * -256.f) - 128.f;   // in [-128,128)
  float f0 = fminf(rintf(r), 127.f);
  a1 = (int)f1; a0 = (int)f0;
}

// 16B LLC-coherent load (same sc0+sc1 bypass semantics as agent-scope atomics,
// legal here because every byte read is flag-ordered: producers drain all 4B
// stores to the LLC before the flag, and we only read after seeing the flag).
__device__ __forceinline__ void issue_l128_cc(const void* p, int4v& d){
  asm volatile("global_load_dwordx4 %0, %1, off sc0 sc1" : "=&v"(d) : "v"(p) : "memory");
}

// ---------- kernel 1: G_in = emb @ w_ih.T + b_ih + b_hh (fp32); h0 -> i8 limb planes ----------
__global__ __launch_bounds__(256) void prep_kernel(
    const float* __restrict__ emb, const float* __restrict__ w_ih,
    const float* __restrict__ b_ih, const float* __restrict__ b_hh,
    const float* __restrict__ h0, float* __restrict__ G_in,
    char* __restrict__ a1buf, char* __restrict__ a0buf)
{
  __shared__ __align__(16) float wt[16 * 512];
  const int tid = threadIdx.x;
  const int colbase = blockIdx.x << 4;       // 16 gate-cols per block
  #pragma unroll
  for (int i = 0; i < 8; ++i){
    int f = tid + (i << 8);                  // 2048 float4 granules
    int r = f >> 7, q = (f & 127) << 2;
    *(float4*)&wt[(r << 9) + q] = *(const float4*)&w_ih[((size_t)(colbase + r) << 9) + q];
  }
  __syncthreads();
  const int v_ = tid & 127, ch = tid >> 7;
  float acc[8] = {0,0,0,0,0,0,0,0};
  const float* ep = emb + ((size_t)v_ << 9);
  for (int kq = 0; kq < 128; ++kq){
    float4 e = *(const float4*)(ep + (kq << 2));
    #pragma unroll
    for (int c = 0; c < 8; ++c){
      float4 w = *(const float4*)&wt[(((ch << 3) + c) << 9) + (kq << 2)]; // LDS broadcast
      acc[c] += e.x * w.x + e.y * w.y + e.z * w.z + e.w * w.w;
    }
  }
  const int col0 = colbase + (ch << 3);
  #pragma unroll
  for (int c = 0; c < 8; ++c) acc[c] += b_ih[col0 + c] + b_hh[col0 + c];
  float* gp = &G_in[((size_t)v_ << 12) + col0];
  float4 r0 = {acc[0], acc[1], acc[2], acc[3]};
  float4 r1 = {acc[4], acc[5], acc[6], acc[7]};
  *(float4*)gp = r0;
  *(float4*)(gp + 4) = r1;

  // h0 -> limb planes, buffer 0
  int g0 = (blockIdx.x << 10) + (tid << 2);
  float4 hv = *(const float4*)&h0[g0];
  int a1x,a0x,a1y,a0y,a1z,a0z,a1w,a0w;
  h_limbs(hv.x, a1x, a0x); h_limbs(hv.y, a1y, a0y);
  h_limbs(hv.z, a1z, a0z); h_limbs(hv.w, a1w, a0w);
  unsigned u1 = (unsigned)(a1x & 255) | ((unsigned)(a1y & 255) << 8)
              | ((unsigned)(a1z & 255) << 16) | ((unsigned)(a1w & 255) << 24);
  unsigned u0 = (unsigned)(a0x & 255) | ((unsigned)(a0y & 255) << 8)
              | ((unsigned)(a0z & 255) << 16) | ((unsigned)(a0w & 255) << 24);
  ((unsigned*)a1buf)[g0 >> 2] = u1;
  ((unsigned*)a0buf)[g0 >> 2] = u0;
}

// ---------- kernel 2: persistent LSTM, exact i8-limb fixed-point recurrent GEMM ----------
// R0's PROVEN agent-scope protocol (sc0+sc1 everywhere on the exchange path).
// Round-5 deltas vs R0 (ordering semantics unchanged):
//   (a) slab staged with 16B sc0+sc1 loads (half the LLC op count of 8B atomics)
//   (b) two-phase wait: poll pieces 0..15 -> issue their loads -> poll 16..31
//       while those loads are in flight -> issue half 2 -> one drain -> LDS.
__global__ __launch_bounds__(256, 1) void lstm_kernel(
    const int* __restrict__ input, const float* __restrict__ c0,
    const float* __restrict__ w_hh, const float* __restrict__ w_out,
    const float* __restrict__ b_out, const float* __restrict__ G_in,
    char* __restrict__ a1base, char* __restrict__ a0base,
    unsigned* __restrict__ flags, float* __restrict__ out)
{
  const int tid  = threadIdx.x;
  const int lane = tid & 63;
  const int wid  = tid >> 6;                 // gate 0..3 (col-tile)
  const int bg   = blockIdx.x >> 5;          // 0..7
  const int cg   = blockIdx.x & 31;          // 0..31
  const int bl   = tid >> 3;                 // 0..31 local batch (elementwise)
  const int u4   = (tid & 7) << 2;           // unit offset 0..28
  const int row  = tid & 31;                 // staging row
  const int grp  = tid >> 5;                 // staging k-group 0..7

  __shared__ __align__(16) unsigned long long sA1[4096]; // 32 KB: full a1 slab, A-frag order
  __shared__ __align__(16) unsigned long long sA0[4096]; // 32 KB: full a0 slab
  __shared__ __align__(16) float sG[32 * 132];           // gates exchange (pad 132)
  __shared__ float sKc[128];                             // per-col 128-offset bias

  // ---- W_hh -> i8 limbs in registers: W*2^19 = b1*256 + b0 ----
  int4v b1f[32], b0f[32];
  {
    const float* wrow = w_hh + (size_t)(wid * 1024 + cg * 32 + (lane & 31)) * 1024;
    const int kb0 = (lane >> 5) << 4;
    float csum = 0.f;
    #pragma unroll
    for (int ks = 0; ks < 32; ++ks){
      B16 v1, v0;
      #pragma unroll
      for (int q = 0; q < 4; ++q){
        float4 w4 = *(const float4*)&wrow[ks * 32 + kb0 + (q << 2)];
        float wa[4] = {w4.x, w4.y, w4.z, w4.w};
        #pragma unroll
        for (int j = 0; j < 4; ++j){
          float w = wa[j];
          csum += w;
          float s1 = rintf(w * 2048.f);                           // W*2^11
          float s0 = fminf(rintf(fmaf(w, 524288.f, s1 * -256.f)), 127.f);
          v1.c[(q << 2) + j] = (signed char)(int)s1;
          v0.c[(q << 2) + j] = (signed char)(int)s0;
        }
      }
      b1f[ks] = v1.v; b0f[ks] = v0.v;
    }
    csum += __shfl_xor(csum, 32, 64);        // full colsum over K=1024
    if (lane < 32) sKc[(wid << 5) + lane] = csum * 0.00390625f; // 128*2^-15*colsum
  }

  const int b = (bg << 5) + bl;
  float4 cr = *(const float4*)&c0[((size_t)b << 10) + (cg << 5) + u4]; // c-state in regs
  unsigned* slots = &flags[bg * 32];         // 32 x u32 = one 128B line per bg
  unsigned* myslot = &flags[bg * 32 + cg];
  const size_t rbase = (size_t)((bg << 5) + row) << 10;

  #pragma unroll 1
  for (int t = 0; t < 128; ++t){
    const char* s1b = a1base + (size_t)(t & 1) * 262144;
    const char* s0b = a0base + (size_t)(t & 1) * 262144;
    char* d1b = a1base + (size_t)((t + 1) & 1) * 262144;
    char* d0b = a0base + (size_t)((t + 1) & 1) * 262144;
    const unsigned target = (unsigned)t;

    // input-side gates via fp32 table gather — no h dependency, issue before the wait
    int iv = input[t * 256 + b];             // harness materializes int inputs as int32
    const float* gp = G_in + ((size_t)iv << 12) + (cg << 5) + u4;
    float4 q0 = *(const float4*)(gp);
    float4 q1 = *(const float4*)(gp + 1024);
    float4 q2 = *(const float4*)(gp + 2048);
    float4 q3 = *(const float4*)(gp + 3072);

    // ---- wait phase 1: wave0 polls pieces 0..15 (one coalesced 128B line) ----
    if (wid == 0 && target){
      int guard = 0;
      for (;;){
        unsigned v = (lane < 32)
          ? __hip_atomic_load(&slots[lane], __ATOMIC_RELAXED, __HIP_MEMORY_SCOPE_AGENT)
          : 0xFFFFFFFFu;
        if (__ballot(lane >= 16 || v >= target) == ~0ull) break;
        if (++guard > (1 << 20)) break;      // safety valve: wrong-but-terminates
      }
    }
    __syncthreads();                         // pieces 0..15 published

    // ---- stage half 1 (units 0..511): issue 16B sc0+sc1 loads, do NOT drain ----
    int4v gv1[8], gv0[8];
    #pragma unroll
    for (int i = 0; i < 4; ++i){
      size_t off = rbase + ((size_t)(grp + (i << 3)) << 4);
      issue_l128_cc(s1b + off, gv1[i]);
      issue_l128_cc(s0b + off, gv0[i]);
    }

    // ---- wait phase 2: poll pieces 16..31 while half-1 loads are in flight ----
    if (wid == 0 && target){
      int guard = 0;
      for (;;){
        unsigned v = (lane < 32)
          ? __hip_atomic_load(&slots[lane], __ATOMIC_RELAXED, __HIP_MEMORY_SCOPE_AGENT)
          : 0xFFFFFFFFu;
        if (__ballot(v >= target) == ~0ull) break;
        if (++guard > (1 << 20)) break;
      }
    }
    __syncthreads();                         // all 32 pieces published

    // ---- stage half 2 (units 512..1023), then one drain for all 16 loads ----
    #pragma unroll
    for (int i = 4; i < 8; ++i){
      size_t off = rbase + ((size_t)(grp + (i << 3)) << 4);
      issue_l128_cc(s1b + off, gv1[i]);
      issue_l128_cc(s0b + off, gv0[i]);
    }
    asm volatile("s_waitcnt vmcnt(0)" ::: "memory");
    __builtin_amdgcn_sched_barrier(0);       // keep ds_writes below the waitcnt
    #pragma unroll
    for (int i = 0; i < 8; ++i){
      int m = grp + (i << 3);
      int lidx = ((((m >> 1) << 6) + ((m & 1) << 5) + row)) << 1;  // ull units, 16B aligned
      *(int4v*)&sA1[lidx] = gv1[i];          // 1 KB contiguous per wave: conflict-free
      *(int4v*)&sA0[lidx] = gv0[i];
    }
    __syncthreads();

    // ---- 96 MFMA over K=1024, 3 independent accumulator chains ----
    i32x16 acc_hi = {}, acc_m1 = {}, acc_m2 = {};
    const int4v* A1 = (const int4v*)sA1;
    const int4v* A0 = (const int4v*)sA0;
    #pragma unroll
    for (int ks = 0; ks < 32; ++ks){
      int4v af1 = A1[(ks << 6) + lane];
      acc_hi = __builtin_amdgcn_mfma_i32_32x32x32_i8(af1, b1f[ks], acc_hi, 0, 0, 0);
      acc_m1 = __builtin_amdgcn_mfma_i32_32x32x32_i8(af1, b0f[ks], acc_m1, 0, 0, 0);
      int4v af0 = A0[(ks << 6) + lane];
      acc_m2 = __builtin_amdgcn_mfma_i32_32x32x32_i8(af0, b1f[ks], acc_m2, 0, 0, 0);
    }

    // combine limb accs -> fp32 gates, dump in C-layout (col=lane&31, row=(r&3)+8*(r>>2)+4*(lane>>5))
    {
      const int col = (wid << 5) + (lane & 31);
      const int rb  = (lane >> 5) << 2;
      #pragma unroll
      for (int r = 0; r < 16; ++r){
        int rrow = (r & 3) + ((r >> 2) << 3) + rb;
        sG[rrow * 132 + col] = 3.814697265625e-06f     * (float)acc_hi[r]             // 2^-18
                             + 1.4901161193847656e-08f * (float)(acc_m1[r] + acc_m2[r]); // 2^-26
      }
    }
    __syncthreads();

    // elementwise LSTM cell update (thread owns (b, 4 consecutive units))
    {
      float4 kI = *(const float4*)&sKc[ 0 + u4];
      float4 kF = *(const float4*)&sKc[32 + u4];
      float4 kG = *(const float4*)&sKc[64 + u4];
      float4 kO = *(const float4*)&sKc[96 + u4];
      float4 gI = *(const float4*)&sG[bl * 132 +  0 + u4];
      float4 gF = *(const float4*)&sG[bl * 132 + 32 + u4];
      float4 gG = *(const float4*)&sG[bl * 132 + 64 + u4];
      float4 gO = *(const float4*)&sG[bl * 132 + 96 + u4];
      int a1x,a0x,a1y,a0y,a1z,a0z,a1w,a0w;
      { float I=sigm(gI.x+q0.x+kI.x), F=sigm(gF.x+q1.x+kF.x), G=tanh_(gG.x+q2.x+kG.x), O=sigm(gO.x+q3.x+kO.x);
        float Cn=F*cr.x+I*G; cr.x=Cn; h_limbs(O*tanh_(Cn), a1x, a0x); }
      { float I=sigm(gI.y+q0.y+kI.y), F=sigm(gF.y+q1.y+kF.y), G=tanh_(gG.y+q2.y+kG.y), O=sigm(gO.y+q3.y+kO.y);
        float Cn=F*cr.y+I*G; cr.y=Cn; h_limbs(O*tanh_(Cn), a1y, a0y); }
      { float I=sigm(gI.z+q0.z+kI.z), F=sigm(gF.z+q1.z+kF.z), G=tanh_(gG.z+q2.z+kG.z), O=sigm(gO.z+q3.z+kO.z);
        float Cn=F*cr.z+I*G; cr.z=Cn; h_limbs(O*tanh_(Cn), a1z, a0z); }
      { float I=sigm(gI.w+q0.w+kI.w), F=sigm(gF.w+q1.w+kF.w), G=tanh_(gG.w+q2.w+kG.w), O=sigm(gO.w+q3.w+kO.w);
        float Cn=F*cr.w+I*G; cr.w=Cn; h_limbs(O*tanh_(Cn), a1w, a0w); }
      unsigned u1 = (unsigned)(a1x & 255) | ((unsigned)(a1y & 255) << 8)
                  | ((unsigned)(a1z & 255) << 16) | ((unsigned)(a1w & 255) << 24);
      unsigned u0 = (unsigned)(a0x & 255) | ((unsigned)(a0y & 255) << 8)
                  | ((unsigned)(a0z & 255) << 16) | ((unsigned)(a0w & 255) << 24);
      size_t eidx = (((size_t)b << 10) + (cg << 5) + u4) >> 2;
      __hip_atomic_store((unsigned*)d1b + eidx, u1, __ATOMIC_RELAXED, __HIP_MEMORY_SCOPE_AGENT);
      __hip_atomic_store((unsigned*)d0b + eidx, u0, __ATOMIC_RELAXED, __HIP_MEMORY_SCOPE_AGENT);
    }
    __syncthreads();   // drains vmcnt(0): h-stores acked at LLC before the slot store below
    if (tid == 0)      // plain slot store — no RMW, no release fence (order via vmcnt drain)
      __hip_atomic_store(myslot, (unsigned)(t + 1), __ATOMIC_RELAXED, __HIP_MEMORY_SCOPE_AGENT);
  }

  // ---- head: out[b, 2cg .. 2cg+1] = h_127 @ w_out.T + b_out (h_127 in buffer 0) ----
  if (wid == 0){
    int guard = 0;
    for (;;){
      unsigned v = (lane < 32)
        ? __hip_atomic_load(&slots[lane], __ATOMIC_RELAXED, __HIP_MEMORY_SCOPE_AGENT)
        : 0xFFFFFFFFu;
      if (__ballot(v >= 128u) == ~0ull) break;
      if (++guard > (1 << 20)) break;
    }
  }
  __syncthreads();
  {
    const unsigned* h1p = (const unsigned*)a1base;
    const unsigned* h0p = (const unsigned*)a0base;
    const int ksl = tid & 7;
    const int o0 = cg << 1;
    float s0 = 0.f, s1 = 0.f;
    const float* w0p = w_out + ((size_t)o0 << 10);
    const float* w1p = w0p + 1024;
    for (int k = ksl * 128; k < ksl * 128 + 128; k += 4){
      size_t idx = (((size_t)b << 10) + k) >> 2;
      unsigned v1 = __hip_atomic_load(h1p + idx, __ATOMIC_RELAXED, __HIP_MEMORY_SCOPE_AGENT);
      unsigned v0 = __hip_atomic_load(h0p + idx, __ATOMIC_RELAXED, __HIP_MEMORY_SCOPE_AGENT);
      float4 w0 = *(const float4*)(w0p + k);
      float4 w1 = *(const float4*)(w1p + k);
      float hh[4];
      #pragma unroll
      for (int j = 0; j < 4; ++j){
        int A1j = (int)(signed char)((v1 >> (8 * j)) & 255);
        int A0j = (int)(signed char)((v0 >> (8 * j)) & 255);
        hh[j] = (float)(A1j * 256 + A0j + 128) * 3.0517578125e-05f;  // 2^-15
      }
      s0 += hh[0]*w0.x + hh[1]*w0.y + hh[2]*w0.z + hh[3]*w0.w;
      s1 += hh[0]*w1.x + hh[1]*w1.y + hh[2]*w1.z + hh[3]*w1.w;
    }
    sG[bl * 16 + (ksl << 1)]     = s0;
    sG[bl * 16 + (ksl << 1) + 1] = s1;
  }
  __syncthreads();
  if (tid < 64){
    int bl2 = tid >> 1, ol = tid & 1;
    float s = b_out[(cg << 1) + ol];
    #pragma unroll
    for (int q = 0; q < 8; ++q) s += sG[bl2 * 16 + (q << 1) + ol];
    out[((size_t)((bg << 5) + bl2) << 6) + (cg << 1) + ol] = s;
  }
}

extern "C" void kernel_launch(void* const* d_in, const int* in_sizes, int n_in,
                              void* d_out, int out_size, void* d_ws, size_t ws_size,
                              hipStream_t stream){
  (void)in_sizes; (void)n_in; (void)out_size; (void)ws_size;
  const int* input   = (const int*)d_in[0];   // harness stores integer inputs as int32
  const float* h0    = (const float*)d_in[1];
  const float* c0    = (const float*)d_in[2];
  const float* emb   = (const float*)d_in[3];
  const float* w_ih  = (const float*)d_in[4];
  const float* w_hh  = (const float*)d_in[5];
  const float* b_ih  = (const float*)d_in[6];
  const float* b_hh  = (const float*)d_in[7];
  const float* w_out = (const float*)d_in[8];
  const float* b_out = (const float*)d_in[9];
  float* out = (float*)d_out;

  char* ws = (char*)d_ws;
  float* G_in   = (float*)ws;                           // 2 MB fp32 [128][4096]
  char* a1buf   = ws + (2u << 20);                      // 512 KB: 2 x i8 plane [256][1024]
  char* a0buf   = ws + (2u << 20) + (512u << 10);       // 512 KB
  unsigned* flags = (unsigned*)(ws + (3u << 20));       // 1 KB slot array (8 bg x 32)

  hipMemsetAsync(flags, 0, 4096, stream);
  prep_kernel<<<dim3(256), dim3(256), 0, stream>>>(emb, w_ih, b_ih, b_hh, h0, G_in, a1buf, a0buf);

  void* args[] = {(void*)&input, (void*)&c0, (void*)&w_hh, (void*)&w_out, (void*)&b_out,
                  (void*)&G_in, (void*)&a1buf, (void*)&a0buf, (void*)&flags, (void*)&out};
  if (hipLaunchCooperativeKernel((void*)lstm_kernel, dim3(256), dim3(256), args, 0, stream)
      != hipSuccess){
    // fallback: 256 blocks at 1 block/CU are de-facto co-resident on a 256-CU device
    lstm_kernel<<<dim3(256), dim3(256), 0, stream>>>(input, c0, w_hh, w_out, b_out,
                                                     G_in, a1buf, a0buf, flags, out);
  }
}

// Round 10
// 1039.378 us; speedup vs baseline: 1.2557x; 1.0539x over previous
//
#include <hip/hip_runtime.h>

typedef __attribute__((ext_vector_type(4)))  int int4v;
typedef __attribute__((ext_vector_type(16))) int i32x16;

union B16 { int4v v; signed char c[16]; };

// ---------- helpers ----------
__device__ __forceinline__ float sigm(float x){ return 1.f / (1.f + __expf(-x)); }
__device__ __forceinline__ float tanh_(float x){
  float e = __expf(-2.f * fabsf(x));        // overflow-safe
  float r = (1.f - e) / (1.f + e);
  return copysignf(r, x);
}
// h in (-1,1): h*2^15 = a1*256 + (a0 + 128), |err| <= 2^-16
__device__ __forceinline__ void h_limbs(float h, int& a1, int& a0){
  float f1 = floorf(h * 128.f);
  f1 = fminf(fmaxf(f1, -128.f), 127.f);
  float r = fmaf(h, 32768.f, f1 * -256.f) - 128.f;   // in [-128,128)
  float f0 = fminf(rintf(r), 127.f);
  a1 = (int)f1; a0 = (int)f0;
}

// 16B LLC-coherent load (same sc0+sc1 bypass semantics as agent-scope atomics,
// legal because every byte read is flag-ordered: producers drain all stores to
// the LLC before the flag, and we only read after seeing the flag).
__device__ __forceinline__ void issue_l128_cc(const void* p, int4v& d){
  asm volatile("global_load_dwordx4 %0, %1, off sc0 sc1" : "=&v"(d) : "v"(p) : "memory");
}

// ---------- kernel 1: G_in = emb @ w_ih.T + b_ih + b_hh (fp32); h0 -> i8 limb planes ----------
__global__ __launch_bounds__(256) void prep_kernel(
    const float* __restrict__ emb, const float* __restrict__ w_ih,
    const float* __restrict__ b_ih, const float* __restrict__ b_hh,
    const float* __restrict__ h0, float* __restrict__ G_in,
    char* __restrict__ a1buf, char* __restrict__ a0buf)
{
  __shared__ __align__(16) float wt[16 * 512];
  const int tid = threadIdx.x;
  const int colbase = blockIdx.x << 4;       // 16 gate-cols per block
  #pragma unroll
  for (int i = 0; i < 8; ++i){
    int f = tid + (i << 8);                  // 2048 float4 granules
    int r = f >> 7, q = (f & 127) << 2;
    *(float4*)&wt[(r << 9) + q] = *(const float4*)&w_ih[((size_t)(colbase + r) << 9) + q];
  }
  __syncthreads();
  const int v_ = tid & 127, ch = tid >> 7;
  float acc[8] = {0,0,0,0,0,0,0,0};
  const float* ep = emb + ((size_t)v_ << 9);
  for (int kq = 0; kq < 128; ++kq){
    float4 e = *(const float4*)(ep + (kq << 2));
    #pragma unroll
    for (int c = 0; c < 8; ++c){
      float4 w = *(const float4*)&wt[(((ch << 3) + c) << 9) + (kq << 2)]; // LDS broadcast
      acc[c] += e.x * w.x + e.y * w.y + e.z * w.z + e.w * w.w;
    }
  }
  const int col0 = colbase + (ch << 3);
  #pragma unroll
  for (int c = 0; c < 8; ++c) acc[c] += b_ih[col0 + c] + b_hh[col0 + c];
  float* gp = &G_in[((size_t)v_ << 12) + col0];
  float4 r0 = {acc[0], acc[1], acc[2], acc[3]};
  float4 r1 = {acc[4], acc[5], acc[6], acc[7]};
  *(float4*)gp = r0;
  *(float4*)(gp + 4) = r1;

  // h0 -> limb planes, buffer 0
  int g0 = (blockIdx.x << 10) + (tid << 2);
  float4 hv = *(const float4*)&h0[g0];
  int a1x,a0x,a1y,a0y,a1z,a0z,a1w,a0w;
  h_limbs(hv.x, a1x, a0x); h_limbs(hv.y, a1y, a0y);
  h_limbs(hv.z, a1z, a0z); h_limbs(hv.w, a1w, a0w);
  unsigned u1 = (unsigned)(a1x & 255) | ((unsigned)(a1y & 255) << 8)
              | ((unsigned)(a1z & 255) << 16) | ((unsigned)(a1w & 255) << 24);
  unsigned u0 = (unsigned)(a0x & 255) | ((unsigned)(a0y & 255) << 8)
              | ((unsigned)(a0z & 255) << 16) | ((unsigned)(a0w & 255) << 24);
  ((unsigned*)a1buf)[g0 >> 2] = u1;
  ((unsigned*)a0buf)[g0 >> 2] = u0;
}

// ---------- kernel 2: persistent LSTM, exact i8-limb fixed-point recurrent GEMM ----------
// R0/R5's PROVEN agent-scope protocol (sc0+sc1 on the exchange path).
// Round-6 delta: chunked slab drain overlapped with MFMA (T3/T4 pattern).
//   poll all 32 pieces -> equalize vmcnt across waves -> issue all 16 slab
//   loads -> for chunk c in 0..3: s_waitcnt vmcnt(12-4c) -> LDS write chunk ->
//   lgkmcnt(0) -> raw s_barrier (NO auto vmcnt(0) drain!) -> 24 MFMA on chunk.
//   Later chunks' loads stay in flight under the earlier chunks' MFMA.
__global__ __launch_bounds__(256, 1) void lstm_kernel(
    const int* __restrict__ input, const float* __restrict__ c0,
    const float* __restrict__ w_hh, const float* __restrict__ w_out,
    const float* __restrict__ b_out, const float* __restrict__ G_in,
    char* __restrict__ a1base, char* __restrict__ a0base,
    unsigned* __restrict__ flags, float* __restrict__ out)
{
  const int tid  = threadIdx.x;
  const int lane = tid & 63;
  const int wid  = tid >> 6;                 // gate 0..3 (col-tile)
  const int bg   = blockIdx.x >> 5;          // 0..7
  const int cg   = blockIdx.x & 31;          // 0..31
  const int bl   = tid >> 3;                 // 0..31 local batch (elementwise)
  const int u4   = (tid & 7) << 2;           // unit offset 0..28
  const int row  = tid & 31;                 // staging row
  const int grp  = tid >> 5;                 // staging k-group 0..7

  __shared__ __align__(16) unsigned long long sA1[4096]; // 32 KB: full a1 slab, A-frag order
  __shared__ __align__(16) unsigned long long sA0[4096]; // 32 KB: full a0 slab
  __shared__ __align__(16) float sG[32 * 132];           // gates exchange (pad 132)
  __shared__ float sKc[128];                             // per-col 128-offset bias

  // ---- W_hh -> i8 limbs in registers: W*2^19 = b1*256 + b0 ----
  int4v b1f[32], b0f[32];
  {
    const float* wrow = w_hh + (size_t)(wid * 1024 + cg * 32 + (lane & 31)) * 1024;
    const int kb0 = (lane >> 5) << 4;
    float csum = 0.f;
    #pragma unroll
    for (int ks = 0; ks < 32; ++ks){
      B16 v1, v0;
      #pragma unroll
      for (int q = 0; q < 4; ++q){
        float4 w4 = *(const float4*)&wrow[ks * 32 + kb0 + (q << 2)];
        float wa[4] = {w4.x, w4.y, w4.z, w4.w};
        #pragma unroll
        for (int j = 0; j < 4; ++j){
          float w = wa[j];
          csum += w;
          float s1 = rintf(w * 2048.f);                           // W*2^11
          float s0 = fminf(rintf(fmaf(w, 524288.f, s1 * -256.f)), 127.f);
          v1.c[(q << 2) + j] = (signed char)(int)s1;
          v0.c[(q << 2) + j] = (signed char)(int)s0;
        }
      }
      b1f[ks] = v1.v; b0f[ks] = v0.v;
    }
    csum += __shfl_xor(csum, 32, 64);        // full colsum over K=1024
    if (lane < 32) sKc[(wid << 5) + lane] = csum * 0.00390625f; // 128*2^-15*colsum
  }

  const int b = (bg << 5) + bl;
  float4 cr = *(const float4*)&c0[((size_t)b << 10) + (cg << 5) + u4]; // c-state in regs
  unsigned* slots = &flags[bg * 32];         // 32 x u32 = one 128B line per bg
  unsigned* myslot = &flags[bg * 32 + cg];
  const size_t rbase = (size_t)((bg << 5) + row) << 10;

  #pragma unroll 1
  for (int t = 0; t < 128; ++t){
    const char* s1b = a1base + (size_t)(t & 1) * 262144;
    const char* s0b = a0base + (size_t)(t & 1) * 262144;
    char* d1b = a1base + (size_t)((t + 1) & 1) * 262144;
    char* d0b = a0base + (size_t)((t + 1) & 1) * 262144;
    const unsigned target = (unsigned)t;

    // input-side gates via fp32 table gather — no h dependency, issue before the wait
    int iv = input[t * 256 + b];             // harness materializes int inputs as int32
    const float* gp = G_in + ((size_t)iv << 12) + (cg << 5) + u4;
    float4 q0 = *(const float4*)(gp);
    float4 q1 = *(const float4*)(gp + 1024);
    float4 q2 = *(const float4*)(gp + 2048);
    float4 q3 = *(const float4*)(gp + 3072);

    // ---- wait: wave0 polls all 32 slots with ONE coalesced 128B load + ballot ----
    if (wid == 0 && target){
      int guard = 0;
      for (;;){
        unsigned v = (lane < 32)
          ? __hip_atomic_load(&slots[lane], __ATOMIC_RELAXED, __HIP_MEMORY_SCOPE_AGENT)
          : 0xFFFFFFFFu;
        if (__ballot(v >= target) == ~0ull) break;
        if (++guard > (1 << 20)) break;      // safety valve: wrong-but-terminates
      }
    }
    __syncthreads();                         // broadcast readiness to all waves

    // equalize outstanding vmem across waves so counted vmcnt below is uniform
    asm volatile("s_waitcnt vmcnt(0)" ::: "memory");
    __builtin_amdgcn_sched_barrier(0);

    // ---- issue ALL 16 slab loads (chunk-major order: iter 2c,2c+1 = chunk c) ----
    int4v gv1[8], gv0[8];
    #pragma unroll
    for (int i = 0; i < 8; ++i){
      size_t off = rbase + ((size_t)(grp + (i << 3)) << 4);
      issue_l128_cc(s1b + off, gv1[i]);
      issue_l128_cc(s0b + off, gv0[i]);
    }

    // ---- chunked drain: LDS-write + MFMA per K=256 chunk, later loads in flight ----
    i32x16 acc_hi = {}, acc_m1 = {}, acc_m2 = {};
    const int4v* A1 = (const int4v*)sA1;
    const int4v* A0 = (const int4v*)sA0;
    #pragma unroll
    for (int c = 0; c < 4; ++c){
      if      (c == 0) asm volatile("s_waitcnt vmcnt(12)" ::: "memory");
      else if (c == 1) asm volatile("s_waitcnt vmcnt(8)"  ::: "memory");
      else if (c == 2) asm volatile("s_waitcnt vmcnt(4)"  ::: "memory");
      else             asm volatile("s_waitcnt vmcnt(0)"  ::: "memory");
      __builtin_amdgcn_sched_barrier(0);
      #pragma unroll
      for (int j = 0; j < 2; ++j){
        const int i = 2*c + j;
        const int m = grp + (i << 3);
        const int lidx = ((((m >> 1) << 6) + ((m & 1) << 5) + row)) << 1; // ull units
        *(int4v*)&sA1[lidx] = gv1[i];
        *(int4v*)&sA0[lidx] = gv0[i];
      }
      asm volatile("s_waitcnt lgkmcnt(0)" ::: "memory");
      __builtin_amdgcn_sched_barrier(0);
      __builtin_amdgcn_s_barrier();          // raw barrier: no auto vmcnt(0) drain
      __builtin_amdgcn_sched_barrier(0);
      #pragma unroll
      for (int ks = 8*c; ks < 8*c + 8; ++ks){
        int4v af1 = A1[(ks << 6) + lane];
        acc_hi = __builtin_amdgcn_mfma_i32_32x32x32_i8(af1, b1f[ks], acc_hi, 0, 0, 0);
        acc_m1 = __builtin_amdgcn_mfma_i32_32x32x32_i8(af1, b0f[ks], acc_m1, 0, 0, 0);
        int4v af0 = A0[(ks << 6) + lane];
        acc_m2 = __builtin_amdgcn_mfma_i32_32x32x32_i8(af0, b1f[ks], acc_m2, 0, 0, 0);
      }
    }

    // combine limb accs -> fp32 gates, dump in C-layout (col=lane&31, row=(r&3)+8*(r>>2)+4*(lane>>5))
    {
      const int col = (wid << 5) + (lane & 31);
      const int rb  = (lane >> 5) << 2;
      #pragma unroll
      for (int r = 0; r < 16; ++r){
        int rrow = (r & 3) + ((r >> 2) << 3) + rb;
        sG[rrow * 132 + col] = 3.814697265625e-06f     * (float)acc_hi[r]             // 2^-18
                             + 1.4901161193847656e-08f * (float)(acc_m1[r] + acc_m2[r]); // 2^-26
      }
    }
    __syncthreads();

    // elementwise LSTM cell update (thread owns (b, 4 consecutive units))
    {
      float4 kI = *(const float4*)&sKc[ 0 + u4];
      float4 kF = *(const float4*)&sKc[32 + u4];
      float4 kG = *(const float4*)&sKc[64 + u4];
      float4 kO = *(const float4*)&sKc[96 + u4];
      float4 gI = *(const float4*)&sG[bl * 132 +  0 + u4];
      float4 gF = *(const float4*)&sG[bl * 132 + 32 + u4];
      float4 gG = *(const float4*)&sG[bl * 132 + 64 + u4];
      float4 gO = *(const float4*)&sG[bl * 132 + 96 + u4];
      int a1x,a0x,a1y,a0y,a1z,a0z,a1w,a0w;
      { float I=sigm(gI.x+q0.x+kI.x), F=sigm(gF.x+q1.x+kF.x), G=tanh_(gG.x+q2.x+kG.x), O=sigm(gO.x+q3.x+kO.x);
        float Cn=F*cr.x+I*G; cr.x=Cn; h_limbs(O*tanh_(Cn), a1x, a0x); }
      { float I=sigm(gI.y+q0.y+kI.y), F=sigm(gF.y+q1.y+kF.y), G=tanh_(gG.y+q2.y+kG.y), O=sigm(gO.y+q3.y+kO.y);
        float Cn=F*cr.y+I*G; cr.y=Cn; h_limbs(O*tanh_(Cn), a1y, a0y); }
      { float I=sigm(gI.z+q0.z+kI.z), F=sigm(gF.z+q1.z+kF.z), G=tanh_(gG.z+q2.z+kG.z), O=sigm(gO.z+q3.z+kO.z);
        float Cn=F*cr.z+I*G; cr.z=Cn; h_limbs(O*tanh_(Cn), a1z, a0z); }
      { float I=sigm(gI.w+q0.w+kI.w), F=sigm(gF.w+q1.w+kF.w), G=tanh_(gG.w+q2.w+kG.w), O=sigm(gO.w+q3.w+kO.w);
        float Cn=F*cr.w+I*G; cr.w=Cn; h_limbs(O*tanh_(Cn), a1w, a0w); }
      unsigned u1 = (unsigned)(a1x & 255) | ((unsigned)(a1y & 255) << 8)
                  | ((unsigned)(a1z & 255) << 16) | ((unsigned)(a1w & 255) << 24);
      unsigned u0 = (unsigned)(a0x & 255) | ((unsigned)(a0y & 255) << 8)
                  | ((unsigned)(a0z & 255) << 16) | ((unsigned)(a0w & 255) << 24);
      size_t eidx = (((size_t)b << 10) + (cg << 5) + u4) >> 2;
      __hip_atomic_store((unsigned*)d1b + eidx, u1, __ATOMIC_RELAXED, __HIP_MEMORY_SCOPE_AGENT);
      __hip_atomic_store((unsigned*)d0b + eidx, u0, __ATOMIC_RELAXED, __HIP_MEMORY_SCOPE_AGENT);
    }
    __syncthreads();   // drains vmcnt(0): h-stores acked at LLC before the slot store below
    if (tid == 0)      // plain slot store — no RMW, no release fence (order via vmcnt drain)
      __hip_atomic_store(myslot, (unsigned)(t + 1), __ATOMIC_RELAXED, __HIP_MEMORY_SCOPE_AGENT);
  }

  // ---- head: out[b, 2cg .. 2cg+1] = h_127 @ w_out.T + b_out (h_127 in buffer 0) ----
  if (wid == 0){
    int guard = 0;
    for (;;){
      unsigned v = (lane < 32)
        ? __hip_atomic_load(&slots[lane], __ATOMIC_RELAXED, __HIP_MEMORY_SCOPE_AGENT)
        : 0xFFFFFFFFu;
      if (__ballot(v >= 128u) == ~0ull) break;
      if (++guard > (1 << 20)) break;
    }
  }
  __syncthreads();
  {
    const unsigned* h1p = (const unsigned*)a1base;
    const unsigned* h0p = (const unsigned*)a0base;
    const int ksl = tid & 7;
    const int o0 = cg << 1;
    float s0 = 0.f, s1 = 0.f;
    const float* w0p = w_out + ((size_t)o0 << 10);
    const float* w1p = w0p + 1024;
    for (int k = ksl * 128; k < ksl * 128 + 128; k += 4){
      size_t idx = (((size_t)b << 10) + k) >> 2;
      unsigned v1 = __hip_atomic_load(h1p + idx, __ATOMIC_RELAXED, __HIP_MEMORY_SCOPE_AGENT);
      unsigned v0 = __hip_atomic_load(h0p + idx, __ATOMIC_RELAXED, __HIP_MEMORY_SCOPE_AGENT);
      float4 w0 = *(const float4*)(w0p + k);
      float4 w1 = *(const float4*)(w1p + k);
      float hh[4];
      #pragma unroll
      for (int j = 0; j < 4; ++j){
        int A1j = (int)(signed char)((v1 >> (8 * j)) & 255);
        int A0j = (int)(signed char)((v0 >> (8 * j)) & 255);
        hh[j] = (float)(A1j * 256 + A0j + 128) * 3.0517578125e-05f;  // 2^-15
      }
      s0 += hh[0]*w0.x + hh[1]*w0.y + hh[2]*w0.z + hh[3]*w0.w;
      s1 += hh[0]*w1.x + hh[1]*w1.y + hh[2]*w1.z + hh[3]*w1.w;
    }
    sG[bl * 16 + (ksl << 1)]     = s0;
    sG[bl * 16 + (ksl << 1) + 1] = s1;
  }
  __syncthreads();
  if (tid < 64){
    int bl2 = tid >> 1, ol = tid & 1;
    float s = b_out[(cg << 1) + ol];
    #pragma unroll
    for (int q = 0; q < 8; ++q) s += sG[bl2 * 16 + (q << 1) + ol];
    out[((size_t)((bg << 5) + bl2) << 6) + (cg << 1) + ol] = s;
  }
}

extern "C" void kernel_launch(void* const* d_in, const int* in_sizes, int n_in,
                              void* d_out, int out_size, void* d_ws, size_t ws_size,
                              hipStream_t stream){
  (void)in_sizes; (void)n_in; (void)out_size; (void)ws_size;
  const int* input   = (const int*)d_in[0];   // harness stores integer inputs as int32
  const float* h0    = (const float*)d_in[1];
  const float* c0    = (const float*)d_in[2];
  const float* emb   = (const float*)d_in[3];
  const float* w_ih  = (const float*)d_in[4];
  const float* w_hh  = (const float*)d_in[5];
  const float* b_ih  = (const float*)d_in[6];
  const float* b_hh  = (const float*)d_in[7];
  const float* w_out = (const float*)d_in[8];
  const float* b_out = (const float*)d_in[9];
  float* out = (float*)d_out;

  char* ws = (char*)d_ws;
  float* G_in   = (float*)ws;                           // 2 MB fp32 [128][4096]
  char* a1buf   = ws + (2u << 20);                      // 512 KB: 2 x i8 plane [256][1024]
  char* a0buf   = ws + (2u << 20) + (512u << 10);       // 512 KB
  unsigned* flags = (unsigned*)(ws + (3u << 20));       // 1 KB slot array (8 bg x 32)

  hipMemsetAsync(flags, 0, 4096, stream);
  prep_kernel<<<dim3(256), dim3(256), 0, stream>>>(emb, w_ih, b_ih, b_hh, h0, G_in, a1buf, a0buf);

  void* args[] = {(void*)&input, (void*)&c0, (void*)&w_hh, (void*)&w_out, (void*)&b_out,
                  (void*)&G_in, (void*)&a1buf, (void*)&a0buf, (void*)&flags, (void*)&out};
  if (hipLaunchCooperativeKernel((void*)lstm_kernel, dim3(256), dim3(256), args, 0, stream)
      != hipSuccess){
    // fallback: 256 blocks at 1 block/CU are de-facto co-resident on a 256-CU device
    lstm_kernel<<<dim3(256), dim3(256), 0, stream>>>(input, c0, w_hh, w_out, b_out,
                                                     G_in, a1buf, a0buf, flags, out);
  }
}

// Round 12
// 1004.414 us; speedup vs baseline: 1.2994x; 1.0348x over previous
//
#include <hip/hip_runtime.h>

typedef __attribute__((ext_vector_type(4)))  int int4v;
typedef __attribute__((ext_vector_type(16))) int i32x16;

union B16 { int4v v; signed char c[16]; };

// ---------- helpers ----------
__device__ __forceinline__ float rcp_(float x){ return __builtin_amdgcn_rcpf(x); }
__device__ __forceinline__ float sigm(float x){ return rcp_(1.f + __expf(-x)); }   // rcp: ~2^-23 rel err, ok vs 2^-16 h-quant
__device__ __forceinline__ float tanh_(float x){
  float e = __expf(-2.f * fabsf(x));        // overflow-safe
  float r = (1.f - e) * rcp_(1.f + e);
  return copysignf(r, x);
}
// h in (-1,1): h*2^15 = a1*256 + (a0 + 128), |err| <= 2^-16
__device__ __forceinline__ void h_limbs(float h, int& a1, int& a0){
  float f1 = floorf(h * 128.f);
  f1 = fminf(fmaxf(f1, -128.f), 127.f);
  float r = fmaf(h, 32768.f, f1 * -256.f) - 128.f;   // in [-128,128)
  float f0 = fminf(rintf(r), 127.f);
  a1 = (int)f1; a0 = (int)f0;
}

// 16B LLC-coherent load (same sc0+sc1 bypass semantics as agent-scope atomics,
// legal because every byte read is flag-ordered: producers drain all stores to
// the LLC before the flag, and we only read after seeing the flag).
__device__ __forceinline__ void issue_l128_cc(const void* p, int4v& d){
  asm volatile("global_load_dwordx4 %0, %1, off sc0 sc1" : "=&v"(d) : "v"(p) : "memory");
}

// ---------- kernel 1: G_in = emb @ w_ih.T + b_ih + b_hh (fp32); h0 -> i8 limb planes ----------
__global__ __launch_bounds__(256) void prep_kernel(
    const float* __restrict__ emb, const float* __restrict__ w_ih,
    const float* __restrict__ b_ih, const float* __restrict__ b_hh,
    const float* __restrict__ h0, float* __restrict__ G_in,
    char* __restrict__ a1buf, char* __restrict__ a0buf)
{
  __shared__ __align__(16) float wt[16 * 512];
  const int tid = threadIdx.x;
  const int colbase = blockIdx.x << 4;       // 16 gate-cols per block
  #pragma unroll
  for (int i = 0; i < 8; ++i){
    int f = tid + (i << 8);                  // 2048 float4 granules
    int r = f >> 7, q = (f & 127) << 2;
    *(float4*)&wt[(r << 9) + q] = *(const float4*)&w_ih[((size_t)(colbase + r) << 9) + q];
  }
  __syncthreads();
  const int v_ = tid & 127, ch = tid >> 7;
  float acc[8] = {0,0,0,0,0,0,0,0};
  const float* ep = emb + ((size_t)v_ << 9);
  for (int kq = 0; kq < 128; ++kq){
    float4 e = *(const float4*)(ep + (kq << 2));
    #pragma unroll
    for (int c = 0; c < 8; ++c){
      float4 w = *(const float4*)&wt[(((ch << 3) + c) << 9) + (kq << 2)]; // LDS broadcast
      acc[c] += e.x * w.x + e.y * w.y + e.z * w.z + e.w * w.w;
    }
  }
  const int col0 = colbase + (ch << 3);
  #pragma unroll
  for (int c = 0; c < 8; ++c) acc[c] += b_ih[col0 + c] + b_hh[col0 + c];
  float* gp = &G_in[((size_t)v_ << 12) + col0];
  float4 r0 = {acc[0], acc[1], acc[2], acc[3]};
  float4 r1 = {acc[4], acc[5], acc[6], acc[7]};
  *(float4*)gp = r0;
  *(float4*)(gp + 4) = r1;

  // h0 -> limb planes, buffer 0
  int g0 = (blockIdx.x << 10) + (tid << 2);
  float4 hv = *(const float4*)&h0[g0];
  int a1x,a0x,a1y,a0y,a1z,a0z,a1w,a0w;
  h_limbs(hv.x, a1x, a0x); h_limbs(hv.y, a1y, a0y);
  h_limbs(hv.z, a1z, a0z); h_limbs(hv.w, a1w, a0w);
  unsigned u1 = (unsigned)(a1x & 255) | ((unsigned)(a1y & 255) << 8)
              | ((unsigned)(a1z & 255) << 16) | ((unsigned)(a1w & 255) << 24);
  unsigned u0 = (unsigned)(a0x & 255) | ((unsigned)(a0y & 255) << 8)
              | ((unsigned)(a0z & 255) << 16) | ((unsigned)(a0w & 255) << 24);
  ((unsigned*)a1buf)[g0 >> 2] = u1;
  ((unsigned*)a0buf)[g0 >> 2] = u0;
}

// ---------- kernel 2: persistent LSTM, exact i8-limb fixed-point recurrent GEMM ----------
// R0/R5's PROVEN agent-scope protocol (sc0+sc1 on the exchange path).
// Round-11 = R10's chunked drain + R5's two-phase poll, composed:
//   poll producers 0..15 -> issue chunk 0,1 loads (exactly their data) ->
//   poll all 32 (hides under those loads) -> issue chunk 2,3 loads ->
//   consume c=0..3 with counted vmcnt(12/8/4/0), raw s_barrier per chunk
//   (no auto vmcnt(0) drain) -> 24 MFMA per chunk while later loads fly.
__global__ __launch_bounds__(256, 1) void lstm_kernel(
    const int* __restrict__ input, const float* __restrict__ c0,
    const float* __restrict__ w_hh, const float* __restrict__ w_out,
    const float* __restrict__ b_out, const float* __restrict__ G_in,
    char* __restrict__ a1base, char* __restrict__ a0base,
    unsigned* __restrict__ flags, float* __restrict__ out)
{
  const int tid  = threadIdx.x;
  const int lane = tid & 63;
  const int wid  = tid >> 6;                 // gate 0..3 (col-tile)
  const int bg   = blockIdx.x >> 5;          // 0..7
  const int cg   = blockIdx.x & 31;          // 0..31
  const int bl   = tid >> 3;                 // 0..31 local batch (elementwise)
  const int u4   = (tid & 7) << 2;           // unit offset 0..28
  const int row  = tid & 31;                 // staging row
  const int grp  = tid >> 5;                 // staging k-group 0..7

  __shared__ __align__(16) unsigned long long sA1[4096]; // 32 KB: full a1 slab, A-frag order
  __shared__ __align__(16) unsigned long long sA0[4096]; // 32 KB: full a0 slab
  __shared__ __align__(16) float sG[32 * 132];           // gates exchange (pad 132)
  __shared__ float sKc[128];                             // per-col 128-offset bias

  // ---- W_hh -> i8 limbs in registers: W*2^19 = b1*256 + b0 ----
  int4v b1f[32], b0f[32];
  {
    const float* wrow = w_hh + (size_t)(wid * 1024 + cg * 32 + (lane & 31)) * 1024;
    const int kb0 = (lane >> 5) << 4;
    float csum = 0.f;
    #pragma unroll
    for (int ks = 0; ks < 32; ++ks){
      B16 v1, v0;
      #pragma unroll
      for (int q = 0; q < 4; ++q){
        float4 w4 = *(const float4*)&wrow[ks * 32 + kb0 + (q << 2)];
        float wa[4] = {w4.x, w4.y, w4.z, w4.w};
        #pragma unroll
        for (int j = 0; j < 4; ++j){
          float w = wa[j];
          csum += w;
          float s1 = rintf(w * 2048.f);                           // W*2^11
          float s0 = fminf(rintf(fmaf(w, 524288.f, s1 * -256.f)), 127.f);
          v1.c[(q << 2) + j] = (signed char)(int)s1;
          v0.c[(q << 2) + j] = (signed char)(int)s0;
        }
      }
      b1f[ks] = v1.v; b0f[ks] = v0.v;
    }
    csum += __shfl_xor(csum, 32, 64);        // full colsum over K=1024
    if (lane < 32) sKc[(wid << 5) + lane] = csum * 0.00390625f; // 128*2^-15*colsum
  }

  const int b = (bg << 5) + bl;
  float4 cr = *(const float4*)&c0[((size_t)b << 10) + (cg << 5) + u4]; // c-state in regs
  unsigned* slots = &flags[bg * 32];         // 32 x u32 = one 128B line per bg
  unsigned* myslot = &flags[bg * 32 + cg];
  const size_t rbase = (size_t)((bg << 5) + row) << 10;

  #pragma unroll 1
  for (int t = 0; t < 128; ++t){
    const char* s1b = a1base + (size_t)(t & 1) * 262144;
    const char* s0b = a0base + (size_t)(t & 1) * 262144;
    char* d1b = a1base + (size_t)((t + 1) & 1) * 262144;
    char* d0b = a0base + (size_t)((t + 1) & 1) * 262144;
    const unsigned target = (unsigned)t;

    // input-side gates via fp32 table gather — no h dependency, issue before the wait
    int iv = input[t * 256 + b];             // harness materializes int inputs as int32
    const float* gp = G_in + ((size_t)iv << 12) + (cg << 5) + u4;
    float4 q0 = *(const float4*)(gp);
    float4 q1 = *(const float4*)(gp + 1024);
    float4 q2 = *(const float4*)(gp + 2048);
    float4 q3 = *(const float4*)(gp + 3072);

    // ---- wait phase 1: producers 0..15 (they feed consume-chunks 0,1) ----
    if (wid == 0 && target){
      int guard = 0;
      for (;;){
        unsigned v = (lane < 32)
          ? __hip_atomic_load(&slots[lane], __ATOMIC_RELAXED, __HIP_MEMORY_SCOPE_AGENT)
          : 0xFFFFFFFFu;
        if (__ballot(lane >= 16 || v >= target) == ~0ull) break;
        if (++guard > (1 << 20)) break;      // safety valve: wrong-but-terminates
      }
    }
    __syncthreads();                         // producers 0..15 published

    // ---- issue chunk 0,1 loads (granules m=grp+8i, i=0..3 -> ks 0..15) ----
    int4v gv1[8], gv0[8];
    #pragma unroll
    for (int i = 0; i < 4; ++i){
      size_t off = rbase + ((size_t)(grp + (i << 3)) << 4);
      issue_l128_cc(s1b + off, gv1[i]);
      issue_l128_cc(s0b + off, gv0[i]);
    }

    // ---- wait phase 2: all 32 producers, while chunk-0/1 loads are in flight ----
    if (wid == 0 && target){
      int guard = 0;
      for (;;){
        unsigned v = (lane < 32)
          ? __hip_atomic_load(&slots[lane], __ATOMIC_RELAXED, __HIP_MEMORY_SCOPE_AGENT)
          : 0xFFFFFFFFu;
        if (__ballot(v >= target) == ~0ull) break;
        if (++guard > (1 << 20)) break;
      }
    }
    __syncthreads();                         // all 32 producers published

    // ---- issue chunk 2,3 loads ----
    #pragma unroll
    for (int i = 4; i < 8; ++i){
      size_t off = rbase + ((size_t)(grp + (i << 3)) << 4);
      issue_l128_cc(s1b + off, gv1[i]);
      issue_l128_cc(s0b + off, gv0[i]);
    }

    // ---- chunked consume: counted vmcnt keeps later chunks' loads in flight.
    //      Safe: vmcnt retires in issue order; stale G_in loads only over-wait. ----
    i32x16 acc_hi = {}, acc_m1 = {}, acc_m2 = {};
    const int4v* A1 = (const int4v*)sA1;
    const int4v* A0 = (const int4v*)sA0;
    #pragma unroll
    for (int c = 0; c < 4; ++c){
      if      (c == 0) asm volatile("s_waitcnt vmcnt(12)" ::: "memory");
      else if (c == 1) asm volatile("s_waitcnt vmcnt(8)"  ::: "memory");
      else if (c == 2) asm volatile("s_waitcnt vmcnt(4)"  ::: "memory");
      else             asm volatile("s_waitcnt vmcnt(0)"  ::: "memory");
      __builtin_amdgcn_sched_barrier(0);
      #pragma unroll
      for (int j = 0; j < 2; ++j){
        const int i = 2*c + j;
        const int m = grp + (i << 3);
        const int lidx = ((((m >> 1) << 6) + ((m & 1) << 5) + row)) << 1; // ull units
        *(int4v*)&sA1[lidx] = gv1[i];
        *(int4v*)&sA0[lidx] = gv0[i];
      }
      asm volatile("s_waitcnt lgkmcnt(0)" ::: "memory");
      __builtin_amdgcn_sched_barrier(0);
      __builtin_amdgcn_s_barrier();          // raw barrier: no auto vmcnt(0) drain
      __builtin_amdgcn_sched_barrier(0);
      #pragma unroll
      for (int ks = 8*c; ks < 8*c + 8; ++ks){
        int4v af1 = A1[(ks << 6) + lane];
        acc_hi = __builtin_amdgcn_mfma_i32_32x32x32_i8(af1, b1f[ks], acc_hi, 0, 0, 0);
        acc_m1 = __builtin_amdgcn_mfma_i32_32x32x32_i8(af1, b0f[ks], acc_m1, 0, 0, 0);
        int4v af0 = A0[(ks << 6) + lane];
        acc_m2 = __builtin_amdgcn_mfma_i32_32x32x32_i8(af0, b1f[ks], acc_m2, 0, 0, 0);
      }
    }

    // combine limb accs -> fp32 gates, dump in C-layout (col=lane&31, row=(r&3)+8*(r>>2)+4*(lane>>5))
    {
      const int col = (wid << 5) + (lane & 31);
      const int rb  = (lane >> 5) << 2;
      #pragma unroll
      for (int r = 0; r < 16; ++r){
        int rrow = (r & 3) + ((r >> 2) << 3) + rb;
        sG[rrow * 132 + col] = 3.814697265625e-06f     * (float)acc_hi[r]             // 2^-18
                             + 1.4901161193847656e-08f * (float)(acc_m1[r] + acc_m2[r]); // 2^-26
      }
    }
    __syncthreads();

    // elementwise LSTM cell update (thread owns (b, 4 consecutive units))
    {
      float4 kI = *(const float4*)&sKc[ 0 + u4];
      float4 kF = *(const float4*)&sKc[32 + u4];
      float4 kG = *(const float4*)&sKc[64 + u4];
      float4 kO = *(const float4*)&sKc[96 + u4];
      float4 gI = *(const float4*)&sG[bl * 132 +  0 + u4];
      float4 gF = *(const float4*)&sG[bl * 132 + 32 + u4];
      float4 gG = *(const float4*)&sG[bl * 132 + 64 + u4];
      float4 gO = *(const float4*)&sG[bl * 132 + 96 + u4];
      int a1x,a0x,a1y,a0y,a1z,a0z,a1w,a0w;
      { float I=sigm(gI.x+q0.x+kI.x), F=sigm(gF.x+q1.x+kF.x), G=tanh_(gG.x+q2.x+kG.x), O=sigm(gO.x+q3.x+kO.x);
        float Cn=F*cr.x+I*G; cr.x=Cn; h_limbs(O*tanh_(Cn), a1x, a0x); }
      { float I=sigm(gI.y+q0.y+kI.y), F=sigm(gF.y+q1.y+kF.y), G=tanh_(gG.y+q2.y+kG.y), O=sigm(gO.y+q3.y+kO.y);
        float Cn=F*cr.y+I*G; cr.y=Cn; h_limbs(O*tanh_(Cn), a1y, a0y); }
      { float I=sigm(gI.z+q0.z+kI.z), F=sigm(gF.z+q1.z+kF.z), G=tanh_(gG.z+q2.z+kG.z), O=sigm(gO.z+q3.z+kO.z);
        float Cn=F*cr.z+I*G; cr.z=Cn; h_limbs(O*tanh_(Cn), a1z, a0z); }
      { float I=sigm(gI.w+q0.w+kI.w), F=sigm(gF.w+q1.w+kF.w), G=tanh_(gG.w+q2.w+kG.w), O=sigm(gO.w+q3.w+kO.w);
        float Cn=F*cr.w+I*G; cr.w=Cn; h_limbs(O*tanh_(Cn), a1w, a0w); }
      unsigned u1 = (unsigned)(a1x & 255) | ((unsigned)(a1y & 255) << 8)
                  | ((unsigned)(a1z & 255) << 16) | ((unsigned)(a1w & 255) << 24);
      unsigned u0 = (unsigned)(a0x & 255) | ((unsigned)(a0y & 255) << 8)
                  | ((unsigned)(a0z & 255) << 16) | ((unsigned)(a0w & 255) << 24);
      size_t eidx = (((size_t)b << 10) + (cg << 5) + u4) >> 2;
      __hip_atomic_store((unsigned*)d1b + eidx, u1, __ATOMIC_RELAXED, __HIP_MEMORY_SCOPE_AGENT);
      __hip_atomic_store((unsigned*)d0b + eidx, u0, __ATOMIC_RELAXED, __HIP_MEMORY_SCOPE_AGENT);
    }
    __syncthreads();   // drains vmcnt(0): h-stores acked at LLC before the slot store below
    if (tid == 0)      // plain slot store — no RMW, no release fence (order via vmcnt drain)
      __hip_atomic_store(myslot, (unsigned)(t + 1), __ATOMIC_RELAXED, __HIP_MEMORY_SCOPE_AGENT);
  }

  // ---- head: out[b, 2cg .. 2cg+1] = h_127 @ w_out.T + b_out (h_127 in buffer 0) ----
  if (wid == 0){
    int guard = 0;
    for (;;){
      unsigned v = (lane < 32)
        ? __hip_atomic_load(&slots[lane], __ATOMIC_RELAXED, __HIP_MEMORY_SCOPE_AGENT)
        : 0xFFFFFFFFu;
      if (__ballot(v >= 128u) == ~0ull) break;
      if (++guard > (1 << 20)) break;
    }
  }
  __syncthreads();
  {
    const unsigned* h1p = (const unsigned*)a1base;
    const unsigned* h0p = (const unsigned*)a0base;
    const int ksl = tid & 7;
    const int o0 = cg << 1;
    float s0 = 0.f, s1 = 0.f;
    const float* w0p = w_out + ((size_t)o0 << 10);
    const float* w1p = w0p + 1024;
    for (int k = ksl * 128; k < ksl * 128 + 128; k += 4){
      size_t idx = (((size_t)b << 10) + k) >> 2;
      unsigned v1 = __hip_atomic_load(h1p + idx, __ATOMIC_RELAXED, __HIP_MEMORY_SCOPE_AGENT);
      unsigned v0 = __hip_atomic_load(h0p + idx, __ATOMIC_RELAXED, __HIP_MEMORY_SCOPE_AGENT);
      float4 w0 = *(const float4*)(w0p + k);
      float4 w1 = *(const float4*)(w1p + k);
      float hh[4];
      #pragma unroll
      for (int j = 0; j < 4; ++j){
        int A1j = (int)(signed char)((v1 >> (8 * j)) & 255);
        int A0j = (int)(signed char)((v0 >> (8 * j)) & 255);
        hh[j] = (float)(A1j * 256 + A0j + 128) * 3.0517578125e-05f;  // 2^-15
      }
      s0 += hh[0]*w0.x + hh[1]*w0.y + hh[2]*w0.z + hh[3]*w0.w;
      s1 += hh[0]*w1.x + hh[1]*w1.y + hh[2]*w1.z + hh[3]*w1.w;
    }
    sG[bl * 16 + (ksl << 1)]     = s0;
    sG[bl * 16 + (ksl << 1) + 1] = s1;
  }
  __syncthreads();
  if (tid < 64){
    int bl2 = tid >> 1, ol = tid & 1;
    float s = b_out[(cg << 1) + ol];
    #pragma unroll
    for (int q = 0; q < 8; ++q) s += sG[bl2 * 16 + (q << 1) + ol];
    out[((size_t)((bg << 5) + bl2) << 6) + (cg << 1) + ol] = s;
  }
}

extern "C" void kernel_launch(void* const* d_in, const int* in_sizes, int n_in,
                              void* d_out, int out_size, void* d_ws, size_t ws_size,
                              hipStream_t stream){
  (void)in_sizes; (void)n_in; (void)out_size; (void)ws_size;
  const int* input   = (const int*)d_in[0];   // harness stores integer inputs as int32
  const float* h0    = (const float*)d_in[1];
  const float* c0    = (const float*)d_in[2];
  const float* emb   = (const float*)d_in[3];
  const float* w_ih  = (const float*)d_in[4];
  const float* w_hh  = (const float*)d_in[5];
  const float* b_ih  = (const float*)d_in[6];
  const float* b_hh  = (const float*)d_in[7];
  const float* w_out = (const float*)d_in[8];
  const float* b_out = (const float*)d_in[9];
  float* out = (float*)d_out;

  char* ws = (char*)d_ws;
  float* G_in   = (float*)ws;                           // 2 MB fp32 [128][4096]
  char* a1buf   = ws + (2u << 20);                      // 512 KB: 2 x i8 plane [256][1024]
  char* a0buf   = ws + (2u << 20) + (512u << 10);       // 512 KB
  unsigned* flags = (unsigned*)(ws + (3u << 20));       // 1 KB slot array (8 bg x 32)

  hipMemsetAsync(flags, 0, 4096, stream);
  prep_kernel<<<dim3(256), dim3(256), 0, stream>>>(emb, w_ih, b_ih, b_hh, h0, G_in, a1buf, a0buf);

  void* args[] = {(void*)&input, (void*)&c0, (void*)&w_hh, (void*)&w_out, (void*)&b_out,
                  (void*)&G_in, (void*)&a1buf, (void*)&a0buf, (void*)&flags, (void*)&out};
  if (hipLaunchCooperativeKernel((void*)lstm_kernel, dim3(256), dim3(256), args, 0, stream)
      != hipSuccess){
    // fallback: 256 blocks at 1 block/CU are de-facto co-resident on a 256-CU device
    lstm_kernel<<<dim3(256), dim3(256), 0, stream>>>(input, c0, w_hh, w_out, b_out,
                                                     G_in, a1buf, a0buf, flags, out);
  }
}

// Round 15
// 943.949 us; speedup vs baseline: 1.3826x; 1.0641x over previous
//
#include <hip/hip_runtime.h>

typedef __attribute__((ext_vector_type(4)))  int int4v;
typedef __attribute__((ext_vector_type(16))) int i32x16;

union B16 { int4v v; signed char c[16]; };

// ---------- helpers ----------
__device__ __forceinline__ float rcp_(float x){ return __builtin_amdgcn_rcpf(x); }
__device__ __forceinline__ float sigm(float x){ return rcp_(1.f + __expf(-x)); }   // rcp: ~2^-23 rel err, ok vs 2^-16 h-quant
__device__ __forceinline__ float tanh_(float x){
  float e = __expf(-2.f * fabsf(x));        // overflow-safe
  float r = (1.f - e) * rcp_(1.f + e);
  return copysignf(r, x);
}
// h in (-1,1): h*2^15 = a1*256 + (a0 + 128), |err| <= 2^-16
__device__ __forceinline__ void h_limbs(float h, int& a1, int& a0){
  float f1 = floorf(h * 128.f);
  f1 = fminf(fmaxf(f1, -128.f), 127.f);
  float r = fmaf(h, 32768.f, f1 * -256.f) - 128.f;   // in [-128,128)
  float f0 = fminf(rintf(r), 127.f);
  a1 = (int)f1; a0 = (int)f0;
}

// 16B LLC-coherent load (same sc0+sc1 bypass semantics as agent-scope atomics,
// legal because every byte read is flag-ordered: producers drain all stores to
// the LLC before the flag, and we only read after seeing the flag).
__device__ __forceinline__ void issue_l128_cc(const void* p, int4v& d){
  asm volatile("global_load_dwordx4 %0, %1, off sc0 sc1" : "=&v"(d) : "v"(p) : "memory");
}

// ---------- kernel 1: G_in = emb @ w_ih.T + b_ih + b_hh (fp32); h0 -> i8 limb planes ----------
__global__ __launch_bounds__(256) void prep_kernel(
    const float* __restrict__ emb, const float* __restrict__ w_ih,
    const float* __restrict__ b_ih, const float* __restrict__ b_hh,
    const float* __restrict__ h0, float* __restrict__ G_in,
    char* __restrict__ a1buf, char* __restrict__ a0buf)
{
  __shared__ __align__(16) float wt[16 * 512];
  const int tid = threadIdx.x;
  const int colbase = blockIdx.x << 4;       // 16 gate-cols per block
  #pragma unroll
  for (int i = 0; i < 8; ++i){
    int f = tid + (i << 8);                  // 2048 float4 granules
    int r = f >> 7, q = (f & 127) << 2;
    *(float4*)&wt[(r << 9) + q] = *(const float4*)&w_ih[((size_t)(colbase + r) << 9) + q];
  }
  __syncthreads();
  const int v_ = tid & 127, ch = tid >> 7;
  float acc[8] = {0,0,0,0,0,0,0,0};
  const float* ep = emb + ((size_t)v_ << 9);
  for (int kq = 0; kq < 128; ++kq){
    float4 e = *(const float4*)(ep + (kq << 2));
    #pragma unroll
    for (int c = 0; c < 8; ++c){
      float4 w = *(const float4*)&wt[(((ch << 3) + c) << 9) + (kq << 2)]; // LDS broadcast
      acc[c] += e.x * w.x + e.y * w.y + e.z * w.z + e.w * w.w;
    }
  }
  const int col0 = colbase + (ch << 3);
  #pragma unroll
  for (int c = 0; c < 8; ++c) acc[c] += b_ih[col0 + c] + b_hh[col0 + c];
  float* gp = &G_in[((size_t)v_ << 12) + col0];
  float4 r0 = {acc[0], acc[1], acc[2], acc[3]};
  float4 r1 = {acc[4], acc[5], acc[6], acc[7]};
  *(float4*)gp = r0;
  *(float4*)(gp + 4) = r1;

  // h0 -> limb planes, buffer 0
  int g0 = (blockIdx.x << 10) + (tid << 2);
  float4 hv = *(const float4*)&h0[g0];
  int a1x,a0x,a1y,a0y,a1z,a0z,a1w,a0w;
  h_limbs(hv.x, a1x, a0x); h_limbs(hv.y, a1y, a0y);
  h_limbs(hv.z, a1z, a0z); h_limbs(hv.w, a1w, a0w);
  unsigned u1 = (unsigned)(a1x & 255) | ((unsigned)(a1y & 255) << 8)
              | ((unsigned)(a1z & 255) << 16) | ((unsigned)(a1w & 255) << 24);
  unsigned u0 = (unsigned)(a0x & 255) | ((unsigned)(a0y & 255) << 8)
              | ((unsigned)(a0z & 255) << 16) | ((unsigned)(a0w & 255) << 24);
  ((unsigned*)a1buf)[g0 >> 2] = u1;
  ((unsigned*)a0buf)[g0 >> 2] = u0;
}

// ---------- kernel 2: persistent LSTM, exact i8-limb fixed-point recurrent GEMM ----------
// Round-13: 512 threads/block (8 waves = 2/SIMD) for TLP over the serial chain.
// Wave w: gate = w&3, K-half = w>>2. half0 owns chunks {0,2}, half1 {1,3} ->
// ping-pong: one half's MFMA overlaps the other half's LDS-write + vmcnt wait
// on the same SIMD. Protocol identical to R12 (proven agent-scope sc0+sc1).
__global__ __launch_bounds__(512, 1) void lstm_kernel(
    const int* __restrict__ input, const float* __restrict__ c0,
    const float* __restrict__ w_hh, const float* __restrict__ w_out,
    const float* __restrict__ b_out, const float* __restrict__ G_in,
    char* __restrict__ a1base, char* __restrict__ a0base,
    unsigned* __restrict__ flags, float* __restrict__ out)
{
  const int tid  = threadIdx.x;
  const int lane = tid & 63;
  const int wid  = tid >> 6;                 // 0..7
  const int gate = wid & 3;
  const int half = wid >> 2;                 // K-half: 0 -> ks{0..7,16..23}, 1 -> ks{8..15,24..31}
  const int bg   = blockIdx.x >> 5;          // 0..7
  const int cg   = blockIdx.x & 31;          // 0..31
  const int row  = tid & 31;                 // staging row
  const int grp  = tid >> 5;                 // staging granule group 0..15

  __shared__ __align__(16) unsigned long long sA1[4096]; // 32 KB: full a1 slab, A-frag order
  __shared__ __align__(16) unsigned long long sA0[4096]; // 32 KB: full a0 slab
  __shared__ __align__(16) float sGa[32 * 132];          // gates partial, half 0
  __shared__ __align__(16) float sGb[32 * 132];          // gates partial, half 1
  __shared__ float sKc2[2][128];                         // per-col 128-offset bias, per half

  // ---- W_hh -> i8 limbs in registers (this wave's 16 K-steps) ----
  int4v b1f[16], b0f[16];
  {
    const float* wrow = w_hh + (size_t)(gate * 1024 + cg * 32 + (lane & 31)) * 1024;
    const int kb0 = (lane >> 5) << 4;
    float csum = 0.f;
    #pragma unroll
    for (int ksl = 0; ksl < 16; ++ksl){
      const int gks = (ksl & 7) + ((ksl >> 3) << 4) + (half << 3); // half0: 0..7,16..23; half1: 8..15,24..31
      B16 v1, v0;
      #pragma unroll
      for (int q = 0; q < 4; ++q){
        float4 w4 = *(const float4*)&wrow[gks * 32 + kb0 + (q << 2)];
        float wa[4] = {w4.x, w4.y, w4.z, w4.w};
        #pragma unroll
        for (int j = 0; j < 4; ++j){
          float w = wa[j];
          csum += w;
          float s1 = rintf(w * 2048.f);                           // W*2^11
          float s0 = fminf(rintf(fmaf(w, 524288.f, s1 * -256.f)), 127.f);
          v1.c[(q << 2) + j] = (signed char)(int)s1;
          v0.c[(q << 2) + j] = (signed char)(int)s0;
        }
      }
      b1f[ksl] = v1.v; b0f[ksl] = v0.v;
    }
    csum += __shfl_xor(csum, 32, 64);        // fold lane halves: per-col partial over this wave's K=512
    if (lane < 32) sKc2[half][(gate << 5) + lane] = csum * 0.00390625f; // 128*2^-15*colsum (partial)
  }

  // cell-update ownership: waves 0..3 (tid<256), thread owns (batch bl, 4 units u4)
  const int bl = (tid >> 3) & 31;
  const int u4 = (tid & 7) << 2;
  const int b  = (bg << 5) + bl;
  float4 cr = {0,0,0,0};
  if (tid < 256) cr = *(const float4*)&c0[((size_t)b << 10) + (cg << 5) + u4];
  unsigned* slots = &flags[bg * 32];         // 32 x u32 = one 128B line per bg
  unsigned* myslot = &flags[bg * 32 + cg];
  const size_t rbase = (size_t)((bg << 5) + row) << 10;

  #pragma unroll 1
  for (int t = 0; t < 128; ++t){
    const char* s1b = a1base + (size_t)(t & 1) * 262144;
    const char* s0b = a0base + (size_t)(t & 1) * 262144;
    char* d1b = a1base + (size_t)((t + 1) & 1) * 262144;
    char* d0b = a0base + (size_t)((t + 1) & 1) * 262144;
    const unsigned target = (unsigned)t;

    // input-side gates (waves 0..3 only — whole waves, so vmcnt counts stay wave-uniform)
    float4 q0 = {0,0,0,0}, q1 = {0,0,0,0}, q2 = {0,0,0,0}, q3 = {0,0,0,0};
    if (tid < 256){
      int iv = input[t * 256 + b];
      const float* gp = G_in + ((size_t)iv << 12) + (cg << 5) + u4;
      q0 = *(const float4*)(gp);
      q1 = *(const float4*)(gp + 1024);
      q2 = *(const float4*)(gp + 2048);
      q3 = *(const float4*)(gp + 3072);
    }

    // ---- wait phase 1: producers 0..15 (units 0..511 -> granules m<32 -> chunks 0,1) ----
    if (wid == 0 && target){
      int guard = 0;
      for (;;){
        unsigned v = (lane < 32)
          ? __hip_atomic_load(&slots[lane], __ATOMIC_RELAXED, __HIP_MEMORY_SCOPE_AGENT)
          : 0xFFFFFFFFu;
        if (__ballot(lane >= 16 || v >= target) == ~0ull) break;
        if (++guard > (1 << 20)) break;      // safety valve: wrong-but-terminates
      }
    }
    __syncthreads();                         // producers 0..15 published

    // ---- issue chunk 0,1 loads: granules m = grp, grp+16 (both planes) ----
    int4v gv1[4], gv0[4];
    #pragma unroll
    for (int i = 0; i < 2; ++i){
      size_t off = rbase + ((size_t)(grp + (i << 4)) << 4);
      issue_l128_cc(s1b + off, gv1[i]);
      issue_l128_cc(s0b + off, gv0[i]);
    }

    // ---- wait phase 2: all 32 producers, while chunk-0/1 loads are in flight ----
    if (wid == 0 && target){
      int guard = 0;
      for (;;){
        unsigned v = (lane < 32)
          ? __hip_atomic_load(&slots[lane], __ATOMIC_RELAXED, __HIP_MEMORY_SCOPE_AGENT)
          : 0xFFFFFFFFu;
        if (__ballot(v >= target) == ~0ull) break;
        if (++guard > (1 << 20)) break;
      }
    }
    __syncthreads();                         // all 32 producers published

    // ---- issue chunk 2,3 loads ----
    #pragma unroll
    for (int i = 2; i < 4; ++i){
      size_t off = rbase + ((size_t)(grp + (i << 4)) << 4);
      issue_l128_cc(s1b + off, gv1[i]);
      issue_l128_cc(s0b + off, gv0[i]);
    }

    // ---- phased consume: phase c writes granules m in [16c,16c+16), then the
    //      owning half (c&1) runs its 24 MFMA while the other half proceeds to
    //      the next phase's vmcnt wait. Counted vmcnt: in-order retire; older
    //      G_in loads only cause over-wait. ----
    i32x16 acc_hi = {}, acc_m1 = {}, acc_m2 = {};
    const int4v* A1 = (const int4v*)sA1;
    const int4v* A0 = (const int4v*)sA0;
    #pragma unroll
    for (int c = 0; c < 4; ++c){
      if      (c == 0) asm volatile("s_waitcnt vmcnt(6)" ::: "memory");
      else if (c == 1) asm volatile("s_waitcnt vmcnt(4)" ::: "memory");
      else if (c == 2) asm volatile("s_waitcnt vmcnt(2)" ::: "memory");
      else             asm volatile("s_waitcnt vmcnt(0)" ::: "memory");
      __builtin_amdgcn_sched_barrier(0);
      {
        const int m = grp + (c << 4);
        const int lidx = ((((m >> 1) << 6) + ((m & 1) << 5) + row)) << 1; // ull units
        *(int4v*)&sA1[lidx] = gv1[c];
        *(int4v*)&sA0[lidx] = gv0[c];
      }
      asm volatile("s_waitcnt lgkmcnt(0)" ::: "memory");
      __builtin_amdgcn_sched_barrier(0);
      __builtin_amdgcn_s_barrier();          // raw barrier: no auto vmcnt(0) drain
      __builtin_amdgcn_sched_barrier(0);
      if (half == (c & 1)){
        const int ksl0 = (c >> 1) << 3;      // local B index base for this chunk
        #pragma unroll
        for (int k8 = 0; k8 < 8; ++k8){
          const int ks  = (c << 3) + k8;     // global K-step (A index)
          const int ksl = ksl0 + k8;         // local B index
          int4v af1 = A1[(ks << 6) + lane];
          acc_hi = __builtin_amdgcn_mfma_i32_32x32x32_i8(af1, b1f[ksl], acc_hi, 0, 0, 0);
          acc_m1 = __builtin_amdgcn_mfma_i32_32x32x32_i8(af1, b0f[ksl], acc_m1, 0, 0, 0);
          int4v af0 = A0[(ks << 6) + lane];
          acc_m2 = __builtin_amdgcn_mfma_i32_32x32x32_i8(af0, b1f[ksl], acc_m2, 0, 0, 0);
        }
      }
    }

    // combine limb accs -> fp32 partial gates into this half's buffer
    // C-layout: col=lane&31, row=(r&3)+8*(r>>2)+4*(lane>>5)
    {
      float* sGh = half ? sGb : sGa;
      const int col = (gate << 5) + (lane & 31);
      const int rb  = (lane >> 5) << 2;
      #pragma unroll
      for (int r = 0; r < 16; ++r){
        int rrow = (r & 3) + ((r >> 2) << 3) + rb;
        sGh[rrow * 132 + col] = 3.814697265625e-06f     * (float)acc_hi[r]             // 2^-18
                              + 1.4901161193847656e-08f * (float)(acc_m1[r] + acc_m2[r]); // 2^-26
      }
    }
    __syncthreads();

    // elementwise LSTM cell update (waves 0..3; thread owns (b, 4 consecutive units))
    if (tid < 256){
      float4 kIa = *(const float4*)&sKc2[0][ 0 + u4], kIb = *(const float4*)&sKc2[1][ 0 + u4];
      float4 kFa = *(const float4*)&sKc2[0][32 + u4], kFb = *(const float4*)&sKc2[1][32 + u4];
      float4 kGa = *(const float4*)&sKc2[0][64 + u4], kGb = *(const float4*)&sKc2[1][64 + u4];
      float4 kOa = *(const float4*)&sKc2[0][96 + u4], kOb = *(const float4*)&sKc2[1][96 + u4];
      float4 gIa = *(const float4*)&sGa[bl * 132 +  0 + u4], gIb = *(const float4*)&sGb[bl * 132 +  0 + u4];
      float4 gFa = *(const float4*)&sGa[bl * 132 + 32 + u4], gFb = *(const float4*)&sGb[bl * 132 + 32 + u4];
      float4 gGa = *(const float4*)&sGa[bl * 132 + 64 + u4], gGb = *(const float4*)&sGb[bl * 132 + 64 + u4];
      float4 gOa = *(const float4*)&sGa[bl * 132 + 96 + u4], gOb = *(const float4*)&sGb[bl * 132 + 96 + u4];
      float4 gI = {gIa.x+gIb.x, gIa.y+gIb.y, gIa.z+gIb.z, gIa.w+gIb.w};
      float4 gF = {gFa.x+gFb.x, gFa.y+gFb.y, gFa.z+gFb.z, gFa.w+gFb.w};
      float4 gG = {gGa.x+gGb.x, gGa.y+gGb.y, gGa.z+gGb.z, gGa.w+gGb.w};
      float4 gO = {gOa.x+gOb.x, gOa.y+gOb.y, gOa.z+gOb.z, gOa.w+gOb.w};
      float4 kI = {kIa.x+kIb.x, kIa.y+kIb.y, kIa.z+kIb.z, kIa.w+kIb.w};
      float4 kF = {kFa.x+kFb.x, kFa.y+kFb.y, kFa.z+kFb.z, kFa.w+kFb.w};
      float4 kG = {kGa.x+kGb.x, kGa.y+kGb.y, kGa.z+kGb.z, kGa.w+kGb.w};
      float4 kO = {kOa.x+kOb.x, kOa.y+kOb.y, kOa.z+kOb.z, kOa.w+kOb.w};
      int a1x,a0x,a1y,a0y,a1z,a0z,a1w,a0w;
      { float I=sigm(gI.x+q0.x+kI.x), F=sigm(gF.x+q1.x+kF.x), G=tanh_(gG.x+q2.x+kG.x), O=sigm(gO.x+q3.x+kO.x);
        float Cn=F*cr.x+I*G; cr.x=Cn; h_limbs(O*tanh_(Cn), a1x, a0x); }
      { float I=sigm(gI.y+q0.y+kI.y), F=sigm(gF.y+q1.y+kF.y), G=tanh_(gG.y+q2.y+kG.y), O=sigm(gO.y+q3.y+kO.y);
        float Cn=F*cr.y+I*G; cr.y=Cn; h_limbs(O*tanh_(Cn), a1y, a0y); }
      { float I=sigm(gI.z+q0.z+kI.z), F=sigm(gF.z+q1.z+kF.z), G=tanh_(gG.z+q2.z+kG.z), O=sigm(gO.z+q3.z+kO.z);
        float Cn=F*cr.z+I*G; cr.z=Cn; h_limbs(O*tanh_(Cn), a1z, a0z); }
      { float I=sigm(gI.w+q0.w+kI.w), F=sigm(gF.w+q1.w+kF.w), G=tanh_(gG.w+q2.w+kG.w), O=sigm(gO.w+q3.w+kO.w);
        float Cn=F*cr.w+I*G; cr.w=Cn; h_limbs(O*tanh_(Cn), a1w, a0w); }
      unsigned u1 = (unsigned)(a1x & 255) | ((unsigned)(a1y & 255) << 8)
                  | ((unsigned)(a1z & 255) << 16) | ((unsigned)(a1w & 255) << 24);
      unsigned u0 = (unsigned)(a0x & 255) | ((unsigned)(a0y & 255) << 8)
                  | ((unsigned)(a0z & 255) << 16) | ((unsigned)(a0w & 255) << 24);
      size_t eidx = (((size_t)b << 10) + (cg << 5) + u4) >> 2;
      __hip_atomic_store((unsigned*)d1b + eidx, u1, __ATOMIC_RELAXED, __HIP_MEMORY_SCOPE_AGENT);
      __hip_atomic_store((unsigned*)d0b + eidx, u0, __ATOMIC_RELAXED, __HIP_MEMORY_SCOPE_AGENT);
    }
    __syncthreads();   // drains vmcnt(0): h-stores acked at LLC before the slot store below
    if (tid == 0)      // plain slot store — no RMW, no release fence (order via vmcnt drain)
      __hip_atomic_store(myslot, (unsigned)(t + 1), __ATOMIC_RELAXED, __HIP_MEMORY_SCOPE_AGENT);
  }

  // ---- head: out[b, 2cg .. 2cg+1] = h_127 @ w_out.T + b_out (h_127 in buffer 0) ----
  if (wid == 0){
    int guard = 0;
    for (;;){
      unsigned v = (lane < 32)
        ? __hip_atomic_load(&slots[lane], __ATOMIC_RELAXED, __HIP_MEMORY_SCOPE_AGENT)
        : 0xFFFFFFFFu;
      if (__ballot(v >= 128u) == ~0ull) break;
      if (++guard > (1 << 20)) break;
    }
  }
  __syncthreads();
  if (tid < 256){
    const unsigned* h1p = (const unsigned*)a1base;
    const unsigned* h0p = (const unsigned*)a0base;
    const int ksl = tid & 7;
    const int o0 = cg << 1;
    float s0 = 0.f, s1 = 0.f;
    const float* w0p = w_out + ((size_t)o0 << 10);
    const float* w1p = w0p + 1024;
    for (int k = ksl * 128; k < ksl * 128 + 128; k += 4){
      size_t idx = (((size_t)b << 10) + k) >> 2;
      unsigned v1 = __hip_atomic_load(h1p + idx, __ATOMIC_RELAXED, __HIP_MEMORY_SCOPE_AGENT);
      unsigned v0 = __hip_atomic_load(h0p + idx, __ATOMIC_RELAXED, __HIP_MEMORY_SCOPE_AGENT);
      float4 w0 = *(const float4*)(w0p + k);
      float4 w1 = *(const float4*)(w1p + k);
      float hh[4];
      #pragma unroll
      for (int j = 0; j < 4; ++j){
        int A1j = (int)(signed char)((v1 >> (8 * j)) & 255);
        int A0j = (int)(signed char)((v0 >> (8 * j)) & 255);
        hh[j] = (float)(A1j * 256 + A0j + 128) * 3.0517578125e-05f;  // 2^-15
      }
      s0 += hh[0]*w0.x + hh[1]*w0.y + hh[2]*w0.z + hh[3]*w0.w;
      s1 += hh[0]*w1.x + hh[1]*w1.y + hh[2]*w1.z + hh[3]*w1.w;
    }
    sGa[bl * 16 + (ksl << 1)]     = s0;
    sGa[bl * 16 + (ksl << 1) + 1] = s1;
  }
  __syncthreads();
  if (tid < 64){
    int bl2 = tid >> 1, ol = tid & 1;
    float s = b_out[(cg << 1) + ol];
    #pragma unroll
    for (int q = 0; q < 8; ++q) s += sGa[bl2 * 16 + (q << 1) + ol];
    out[((size_t)((bg << 5) + bl2) << 6) + (cg << 1) + ol] = s;
  }
}

extern "C" void kernel_launch(void* const* d_in, const int* in_sizes, int n_in,
                              void* d_out, int out_size, void* d_ws, size_t ws_size,
                              hipStream_t stream){
  (void)in_sizes; (void)n_in; (void)out_size; (void)ws_size;
  const int* input   = (const int*)d_in[0];   // harness stores integer inputs as int32
  const float* h0    = (const float*)d_in[1];
  const float* c0    = (const float*)d_in[2];
  const float* emb   = (const float*)d_in[3];
  const float* w_ih  = (const float*)d_in[4];
  const float* w_hh  = (const float*)d_in[5];
  const float* b_ih  = (const float*)d_in[6];
  const float* b_hh  = (const float*)d_in[7];
  const float* w_out = (const float*)d_in[8];
  const float* b_out = (const float*)d_in[9];
  float* out = (float*)d_out;

  char* ws = (char*)d_ws;
  float* G_in   = (float*)ws;                           // 2 MB fp32 [128][4096]
  char* a1buf   = ws + (2u << 20);                      // 512 KB: 2 x i8 plane [256][1024]
  char* a0buf   = ws + (2u << 20) + (512u << 10);       // 512 KB
  unsigned* flags = (unsigned*)(ws + (3u << 20));       // 1 KB slot array (8 bg x 32)

  hipMemsetAsync(flags, 0, 4096, stream);
  prep_kernel<<<dim3(256), dim3(256), 0, stream>>>(emb, w_ih, b_ih, b_hh, h0, G_in, a1buf, a0buf);

  void* args[] = {(void*)&input, (void*)&c0, (void*)&w_hh, (void*)&w_out, (void*)&b_out,
                  (void*)&G_in, (void*)&a1buf, (void*)&a0buf, (void*)&flags, (void*)&out};
  if (hipLaunchCooperativeKernel((void*)lstm_kernel, dim3(256), dim3(512), args, 0, stream)
      != hipSuccess){
    // fallback: 256 blocks at 1 block/CU (LDS ~98 KB caps 1/CU) are de-facto co-resident
    lstm_kernel<<<dim3(256), dim3(512), 0, stream>>>(input, c0, w_hh, w_out, b_out,
                                                     G_in, a1buf, a0buf, flags, out);
  }
}